// Round 18
// baseline (479.540 us; speedup 1.0000x reference)
//
#include <hip/hip_runtime.h>
#include <hip/hip_bf16.h>

// GNODE fully fused: y' = relu(y@W1+b1)@W2+b2, RK4(3/8) x10 steps (h=0.1),
// out = y@Wl+bl.  N=200000 rows, 128 ch, 64 out ch.
//
// Round 18 = r17 (4-way channel split, fp32 state, 466us, MfmaUtil 46/
// VALU-only ~8 / stalls ~46%) + DUAL ROW-TILE pipelining.  Each wave now
// runs TWO 16-row tiles (A,B) of its channel quarter:
//   - each barrier serves BOTH tiles -> barriers per tile-feval halved
//     (the ~46% stall component is barrier+LDS-latency);
//   - tile B's frag build + LDS reads interleave with tile A's MFMA chain
//     -> stalls filled even at 2 waves/SIMD.
// Why this won't repeat r15's blowup: 4-way split's per-tile state is 24
// regs (vs 96 at 2-way) -> arch ~100 (state 48 + transients 32 + misc),
// AGPR ~96 (weights 64 + acc 32); total ~195 -> 2-3 waves/SIMD.
//
// Structure: block = 256 thr = 4 waves, 32 rows (2 tiles x 16); wave wid
// owns out-ch [32wid,+32) of both layers; weights 16 A-frags = 64 regs
// (AGPR-resident).  B-frag kb == wave kb's 8 state elems -> exchange =
// write 1, read 3 per tile.
//
// State recurrences (template<MODE>):
//   M1: U<-k1   M2: V<-k2   M3: U<-U+3(V+k3), V<-U-V+k3   M4: y+=h/8(U+k4)
// Layout identity (mfma_f32_16x16x32_bf16, HW-verified m89):
//   D:      ch = 16*MB + 4*(lane>>4) + r,               batch = lane&15
//   B-frag: ch = 32*kb + 16*(j>>2) + 4*(lane>>4)+(j&3),  batch = lane&15
// => frag[kb][j] = state[8*kb + j]; wave wid owns MB {2wid,2wid+1}, i.e.
//    state elems [8wid, 8wid+8).  All lane-local.
// Barrier safety: 2 barriers/feval on alternating buffer sets (arg*, hx*).

typedef __attribute__((ext_vector_type(8))) short bf16x8;
typedef __attribute__((ext_vector_type(4))) float f32x4;

constexpr float HS = 0.1f;

__device__ __forceinline__ short bf16s(float f) {
    return __builtin_bit_cast(short, (__bf16)f);      // -> v_cvt_pk_bf16_f32 (paired)
}
__device__ __forceinline__ bf16x8 bc8(uint4 u) { return __builtin_bit_cast(bf16x8, u); }

#define MFMA_BF16 __builtin_amdgcn_mfma_f32_16x16x32_bf16

// Own B-frag (8 elems) from fp32 y/U/V, RK4 combo fused per mode.
template<int M>
__device__ __forceinline__ bf16x8 build_frag(const float (&y)[8], const float (&U)[8],
                                             const float (&V)[8]) {
    bf16x8 f;
    #pragma unroll
    for (int j = 0; j < 8; ++j) {
        float v;
        if (M == 1)      v = y[j];
        else if (M == 2) v = fmaf(HS * (1.f / 3.f), U[j], y[j]);
        else if (M == 3) v = fmaf(-HS * (1.f / 3.f), U[j], fmaf(HS, V[j], y[j]));
        else             v = fmaf(HS, V[j], y[j]);
        f[j] = bf16s(v);
    }
    return f;
}

// Mode-fused writeback for one tile (e = 4*mb + r, all fp32).
template<int M>
__device__ __forceinline__ void writeback(const f32x4 (&a2)[2], float (&y)[8],
                                          float (&U)[8], float (&V)[8]) {
    #pragma unroll
    for (int e = 0; e < 8; ++e) {
        const float k = a2[e >> 2][e & 3];
        if (M == 1)      U[e] = k;
        else if (M == 2) V[e] = k;
        else if (M == 3) {
            const float u = U[e], v = V[e];
            U[e] = fmaf(3.f, v + k, u);
            V[e] = u - v + k;
        } else {
            y[e] = fmaf(HS * 0.125f, U[e] + k, y[e]);
        }
    }
}

// One f-eval for BOTH row-tiles of this wave's 32-out-ch quarter.
template<int M>
__device__ __forceinline__ void feval2(const bf16x8 (&w1r)[8], const bf16x8 (&w2r)[8],
                                       const float* __restrict__ sbf1,
                                       const float* __restrict__ sbf2,
                                       uint4* __restrict__ myA,
                                       const uint4* __restrict__ oa1A,
                                       const uint4* __restrict__ oa2A,
                                       const uint4* __restrict__ oa3A,
                                       uint4* __restrict__ myB,
                                       const uint4* __restrict__ oa1B,
                                       const uint4* __restrict__ oa2B,
                                       const uint4* __restrict__ oa3B,
                                       uint4* __restrict__ myHA,
                                       const uint4* __restrict__ oh1A,
                                       const uint4* __restrict__ oh2A,
                                       const uint4* __restrict__ oh3A,
                                       uint4* __restrict__ myHB,
                                       const uint4* __restrict__ oh1B,
                                       const uint4* __restrict__ oh2B,
                                       const uint4* __restrict__ oh3B,
                                       float (&yA)[8], float (&UA)[8], float (&VA)[8],
                                       float (&yB)[8], float (&UB)[8], float (&VB)[8])
{
    // ---- own arg frags -> LDS; bias init overlaps the barrier
    const bf16x8 a0A = build_frag<M>(yA, UA, VA);
    const bf16x8 a0B = build_frag<M>(yB, UB, VB);
    *myA = __builtin_bit_cast(uint4, a0A);
    *myB = __builtin_bit_cast(uint4, a0B);
    f32x4 accA[2], accB[2];
    accA[0] = *(const f32x4*)&sbf1[0];
    accA[1] = *(const f32x4*)&sbf1[16];
    accB[0] = accA[0];
    accB[1] = accA[1];
    __syncthreads();
    const bf16x8 a1A = bc8(*oa1A), a2A = bc8(*oa2A), a3A = bc8(*oa3A);
    const bf16x8 a1B = bc8(*oa1B), a2B = bc8(*oa2B), a3B = bc8(*oa3B);

    // ---- matmul1: 16 MFMA, tiles interleaved (independent chains)
    __builtin_amdgcn_s_setprio(1);
    accA[0] = MFMA_BF16(w1r[0], a0A, accA[0], 0, 0, 0);
    accB[0] = MFMA_BF16(w1r[0], a0B, accB[0], 0, 0, 0);
    accA[1] = MFMA_BF16(w1r[4], a0A, accA[1], 0, 0, 0);
    accB[1] = MFMA_BF16(w1r[4], a0B, accB[1], 0, 0, 0);
    accA[0] = MFMA_BF16(w1r[1], a1A, accA[0], 0, 0, 0);
    accB[0] = MFMA_BF16(w1r[1], a1B, accB[0], 0, 0, 0);
    accA[1] = MFMA_BF16(w1r[5], a1A, accA[1], 0, 0, 0);
    accB[1] = MFMA_BF16(w1r[5], a1B, accB[1], 0, 0, 0);
    accA[0] = MFMA_BF16(w1r[2], a2A, accA[0], 0, 0, 0);
    accB[0] = MFMA_BF16(w1r[2], a2B, accB[0], 0, 0, 0);
    accA[1] = MFMA_BF16(w1r[6], a2A, accA[1], 0, 0, 0);
    accB[1] = MFMA_BF16(w1r[6], a2B, accB[1], 0, 0, 0);
    accA[0] = MFMA_BF16(w1r[3], a3A, accA[0], 0, 0, 0);
    accB[0] = MFMA_BF16(w1r[3], a3B, accB[0], 0, 0, 0);
    accA[1] = MFMA_BF16(w1r[7], a3A, accA[1], 0, 0, 0);
    accB[1] = MFMA_BF16(w1r[7], a3B, accB[1], 0, 0, 0);
    __builtin_amdgcn_s_setprio(0);

    // ---- relu -> own h frags (adjacent pairs: packable cvt)
    bf16x8 hbA, hbB;
    #pragma unroll
    for (int j = 0; j < 8; ++j) {
        hbA[j] = bf16s(fmaxf(accA[j >> 2][j & 3], 0.f));
        hbB[j] = bf16s(fmaxf(accB[j >> 2][j & 3], 0.f));
    }
    *myHA = __builtin_bit_cast(uint4, hbA);
    *myHB = __builtin_bit_cast(uint4, hbB);
    f32x4 c2A[2], c2B[2];
    c2A[0] = *(const f32x4*)&sbf2[0];
    c2A[1] = *(const f32x4*)&sbf2[16];
    c2B[0] = c2A[0];
    c2B[1] = c2A[1];
    __syncthreads();
    const bf16x8 h1A = bc8(*oh1A), h2A = bc8(*oh2A), h3A = bc8(*oh3A);
    const bf16x8 h1B = bc8(*oh1B), h2B = bc8(*oh2B), h3B = bc8(*oh3B);

    // ---- matmul2: 16 MFMA
    __builtin_amdgcn_s_setprio(1);
    c2A[0] = MFMA_BF16(w2r[0], hbA, c2A[0], 0, 0, 0);
    c2B[0] = MFMA_BF16(w2r[0], hbB, c2B[0], 0, 0, 0);
    c2A[1] = MFMA_BF16(w2r[4], hbA, c2A[1], 0, 0, 0);
    c2B[1] = MFMA_BF16(w2r[4], hbB, c2B[1], 0, 0, 0);
    c2A[0] = MFMA_BF16(w2r[1], h1A, c2A[0], 0, 0, 0);
    c2B[0] = MFMA_BF16(w2r[1], h1B, c2B[0], 0, 0, 0);
    c2A[1] = MFMA_BF16(w2r[5], h1A, c2A[1], 0, 0, 0);
    c2B[1] = MFMA_BF16(w2r[5], h1B, c2B[1], 0, 0, 0);
    c2A[0] = MFMA_BF16(w2r[2], h2A, c2A[0], 0, 0, 0);
    c2B[0] = MFMA_BF16(w2r[2], h2B, c2B[0], 0, 0, 0);
    c2A[1] = MFMA_BF16(w2r[6], h2A, c2A[1], 0, 0, 0);
    c2B[1] = MFMA_BF16(w2r[6], h2B, c2B[1], 0, 0, 0);
    c2A[0] = MFMA_BF16(w2r[3], h3A, c2A[0], 0, 0, 0);
    c2B[0] = MFMA_BF16(w2r[3], h3B, c2B[0], 0, 0, 0);
    c2A[1] = MFMA_BF16(w2r[7], h3A, c2A[1], 0, 0, 0);
    c2B[1] = MFMA_BF16(w2r[7], h3B, c2B[1], 0, 0, 0);
    __builtin_amdgcn_s_setprio(0);

    // ---- writebacks
    writeback<M>(c2A, yA, UA, VA);
    writeback<M>(c2B, yB, UB, VB);
}

__global__ __launch_bounds__(256) void gnode_kernel(
    const float* __restrict__ x, const uint4* __restrict__ wfr,
    const float* __restrict__ b1, const float* __restrict__ b2,
    const float* __restrict__ bl, float* __restrict__ out, int n)
{
    __shared__ uint4 argA[4][64], argB[4][64];   // 8KB arg exchange (tiles A,B)
    __shared__ uint4 hxA[4][64],  hxB[4][64];    // 8KB h exchange
    __shared__ float s_bf[256];                  // 1KB biases

    const int tid  = threadIdx.x;
    const int lane = tid & 63;
    const int wid  = tid >> 6;       // 0..3: which 32-out-ch quarter
    const int g    = lane >> 4;
    const int c16  = lane & 15;
    const int rowA = blockIdx.x * 32 + c16;      // tile A row
    const int rowB = rowA + 16;                  // tile B row
    const int rcA  = rowA < n ? rowA : n - 1;
    const int rcB  = rowB < n ? rowB : n - 1;

    if (wid < 2) s_bf[tid & 127]         = b1[tid & 127];   // waves 0,1 write b1
    else         s_bf[128 + (tid & 127)] = b2[tid & 127];   // waves 2,3 write b2

    // ---- weights: this wave's quarters, wid-RELATIVE kb order kl -> (wid+kl)&3
    bf16x8 w1r[8], w2r[8];
    #pragma unroll
    for (int f = 0; f < 8; ++f) {
        const int mb = f >> 2, kl = f & 3;
        const int kg = (wid + kl) & 3;
        w1r[f] = bc8(wfr[((2 * wid + mb) * 4 + kg) * 64 + lane]);
        w2r[f] = bc8(wfr[(32 + (2 * wid + mb) * 4 + kg) * 64 + lane]);
    }

    // ---- hoisted LDS pointers
    uint4*       myA  = &argA[wid][lane];
    const uint4* oa1A = &argA[(wid + 1) & 3][lane];
    const uint4* oa2A = &argA[(wid + 2) & 3][lane];
    const uint4* oa3A = &argA[(wid + 3) & 3][lane];
    uint4*       myB  = &argB[wid][lane];
    const uint4* oa1B = &argB[(wid + 1) & 3][lane];
    const uint4* oa2B = &argB[(wid + 2) & 3][lane];
    const uint4* oa3B = &argB[(wid + 3) & 3][lane];
    uint4*       myHA = &hxA[wid][lane];
    const uint4* oh1A = &hxA[(wid + 1) & 3][lane];
    const uint4* oh2A = &hxA[(wid + 2) & 3][lane];
    const uint4* oh3A = &hxA[(wid + 3) & 3][lane];
    uint4*       myHB = &hxB[wid][lane];
    const uint4* oh1B = &hxB[(wid + 1) & 3][lane];
    const uint4* oh2B = &hxB[(wid + 2) & 3][lane];
    const uint4* oh3B = &hxB[(wid + 3) & 3][lane];
    const float* sbf1 = &s_bf[32 * wid + 4 * g];
    const float* sbf2 = &s_bf[128 + 32 * wid + 4 * g];

    // ---- state: per tile 8 elems (ch = 32wid + 16t + 4g + r, t = e>>2)
    float yA[8], yB[8];
    {
        const f32x4* x4 = (const f32x4*)x;
        const f32x4 vA0 = x4[(size_t)rcA * 32 + 8 * wid + g];
        const f32x4 vA1 = x4[(size_t)rcA * 32 + 8 * wid + 4 + g];
        const f32x4 vB0 = x4[(size_t)rcB * 32 + 8 * wid + g];
        const f32x4 vB1 = x4[(size_t)rcB * 32 + 8 * wid + 4 + g];
        #pragma unroll
        for (int r = 0; r < 4; ++r) {
            yA[r] = vA0[r]; yA[4 + r] = vA1[r];
            yB[r] = vB0[r]; yB[4 + r] = vB1[r];
        }
    }
    __syncthreads();

    float UA[8], VA[8], UB[8], VB[8];

    #pragma unroll 1
    for (int st = 0; st < 10; ++st) {
        feval2<1>(w1r, w2r, sbf1, sbf2, myA, oa1A, oa2A, oa3A, myB, oa1B, oa2B, oa3B,
                  myHA, oh1A, oh2A, oh3A, myHB, oh1B, oh2B, oh3B,
                  yA, UA, VA, yB, UB, VB);
        feval2<2>(w1r, w2r, sbf1, sbf2, myA, oa1A, oa2A, oa3A, myB, oa1B, oa2B, oa3B,
                  myHA, oh1A, oh2A, oh3A, myHB, oh1B, oh2B, oh3B,
                  yA, UA, VA, yB, UB, VB);
        feval2<3>(w1r, w2r, sbf1, sbf2, myA, oa1A, oa2A, oa3A, myB, oa1B, oa2B, oa3B,
                  myHA, oh1A, oh2A, oh3A, myHB, oh1B, oh2B, oh3B,
                  yA, UA, VA, yB, UB, VB);
        feval2<4>(w1r, w2r, sbf1, sbf2, myA, oa1A, oa2A, oa3A, myB, oa1B, oa2B, oa3B,
                  myHA, oh1A, oh2A, oh3A, myHB, oh1B, oh2B, oh3B,
                  yA, UA, VA, yB, UB, VB);
    }

    // ---- epilogue: out^T = Wl^T y^T + bl (wave computes out-ch [16wid,+16))
    bf16x8 yfA, yfB;
    #pragma unroll
    for (int j = 0; j < 8; ++j) { yfA[j] = bf16s(yA[j]); yfB[j] = bf16s(yB[j]); }
    *myA = __builtin_bit_cast(uint4, yfA);
    *myB = __builtin_bit_cast(uint4, yfB);
    __syncthreads();
    const bf16x8 yA1 = bc8(*oa1A), yA2 = bc8(*oa2A), yA3 = bc8(*oa3A);
    const bf16x8 yB1 = bc8(*oa1B), yB2 = bc8(*oa2B), yB3 = bc8(*oa3B);

    f32x4 aoA = ((const f32x4*)bl)[wid * 4 + g];         // bl[16wid + 4g + r]
    f32x4 aoB = aoA;
    {
        const int fb = 64 + wid * 4;                     // Wl frag base, global kb order
        const bf16x8 wl0 = bc8(wfr[(fb + ((wid + 0) & 3)) * 64 + lane]);
        const bf16x8 wl1 = bc8(wfr[(fb + ((wid + 1) & 3)) * 64 + lane]);
        const bf16x8 wl2 = bc8(wfr[(fb + ((wid + 2) & 3)) * 64 + lane]);
        const bf16x8 wl3 = bc8(wfr[(fb + ((wid + 3) & 3)) * 64 + lane]);
        aoA = MFMA_BF16(wl0, yfA, aoA, 0, 0, 0);
        aoB = MFMA_BF16(wl0, yfB, aoB, 0, 0, 0);
        aoA = MFMA_BF16(wl1, yA1, aoA, 0, 0, 0);
        aoB = MFMA_BF16(wl1, yB1, aoB, 0, 0, 0);
        aoA = MFMA_BF16(wl2, yA2, aoA, 0, 0, 0);
        aoB = MFMA_BF16(wl2, yB2, aoB, 0, 0, 0);
        aoA = MFMA_BF16(wl3, yA3, aoA, 0, 0, 0);
        aoB = MFMA_BF16(wl3, yB3, aoB, 0, 0, 0);
    }
    if (rowA < n)
        ((f32x4*)out)[(size_t)rowA * 16 + wid * 4 + g] = aoA;   // out[row][16wid+4g+r]
    if (rowB < n)
        ((f32x4*)out)[(size_t)rowB * 16 + wid * 4 + g] = aoB;
}

// ---- prep: A-frag-linear bf16 weights into d_ws ----
// A-frag (16x32): lane l, elem j:  row = l&15 (+16*MB),
//                                  k   = 32*kb + 16*(j>>2) + 4*(l>>4) + (j&3)
// wfr[f*64+lane] : f 0..31 = W1 (MB=f>>2,kb=f&3), 32..63 = W2, 64..79 = Wl.
__global__ void prep_kernel(const float* __restrict__ W1, const float* __restrict__ W2,
                            const float* __restrict__ Wl, uint4* __restrict__ wfr)
{
    int t = blockIdx.x * 256 + threadIdx.x;
    if (t >= 80 * 64) return;
    int f = t >> 6, lane = t & 63;
    int gq = lane >> 4, c = lane & 15;
    const float* W; int mb, kv, cols;
    if (f < 32)      { W = W1; mb = f >> 2;        kv = f & 3;        cols = 128; }
    else if (f < 64) { W = W2; mb = (f - 32) >> 2; kv = (f - 32) & 3; cols = 128; }
    else             { W = Wl; mb = (f - 64) >> 2; kv = (f - 64) & 3; cols = 64;  }
    int col = mb * 16 + c;               // output-channel (A row)
    unsigned short v[8];
    #pragma unroll
    for (int j = 0; j < 8; ++j) {
        int k = kv * 32 + (j >> 2) * 16 + gq * 4 + (j & 3);
        v[j] = (unsigned short)__builtin_bit_cast(short, (__bf16)W[k * cols + col]);
    }
    uint4 o;
    o.x = (unsigned)v[0] | ((unsigned)v[1] << 16);
    o.y = (unsigned)v[2] | ((unsigned)v[3] << 16);
    o.z = (unsigned)v[4] | ((unsigned)v[5] << 16);
    o.w = (unsigned)v[6] | ((unsigned)v[7] << 16);
    wfr[t] = o;
}

extern "C" void kernel_launch(void* const* d_in, const int* in_sizes, int n_in,
                              void* d_out, int out_size, void* d_ws, size_t ws_size,
                              hipStream_t stream)
{
    const float* x  = (const float*)d_in[0];
    const float* W1 = (const float*)d_in[1];
    const float* b1 = (const float*)d_in[2];
    const float* W2 = (const float*)d_in[3];
    const float* b2 = (const float*)d_in[4];
    const float* Wl = (const float*)d_in[5];
    const float* bl = (const float*)d_in[6];

    const int n = in_sizes[0] / 128;

    uint4* wfr = (uint4*)d_ws;                       // 80*64*16 = 81920 B

    prep_kernel<<<20, 256, 0, stream>>>(W1, W2, Wl, wfr);

    const int nb = (n + 31) / 32;            // 32 rows per block (4 waves x 2 tiles)
    gnode_kernel<<<nb, 256, 0, stream>>>(x, wfr, b1, b2, bl, (float*)d_out, n);
}